// Round 13
// baseline (157.687 us; speedup 1.0000x reference)
//
#include <hip/hip_runtime.h>
#include <hip/hip_bf16.h>

#define B_   1024
#define T_   85
#define DIN  20
#define H_   1024
#define C_   27
#define OBJ_ (T_ * 36)   // 3060
#define TOUT (T_ - 1)    // 84

typedef unsigned short u16;
typedef __attribute__((ext_vector_type(8))) short bf16x8;
typedef __attribute__((ext_vector_type(4))) float f32x4;

__device__ __forceinline__ u16 f2bf(float f) {
    __hip_bfloat16 h = __float2bfloat16(f);
    return *reinterpret_cast<u16*>(&h);
}
__device__ __forceinline__ float bf2f(u16 u) {
    __hip_bfloat16 h;
    *reinterpret_cast<u16*>(&h) = u;
    return __bfloat162float(h);
}
__device__ __forceinline__ int f_as_i(float f) {
    union { float f; int i; } u; u.f = f; return u.i;
}
__device__ __forceinline__ float i_as_f(int i) {
    union { float f; int i; } u; u.i = i; return u.f;
}

// 64-lane sum via DPP (VALU pipe): row_shr 1/2/4/8 + bcast15 + bcast31,
// total lands in lane 63; readlane broadcasts to all lanes.
__device__ __forceinline__ float wave64_sum_bcast(float p) {
    p += i_as_f(__builtin_amdgcn_update_dpp(0, f_as_i(p), 0x111, 0xf, 0xf, true));
    p += i_as_f(__builtin_amdgcn_update_dpp(0, f_as_i(p), 0x112, 0xf, 0xf, true));
    p += i_as_f(__builtin_amdgcn_update_dpp(0, f_as_i(p), 0x114, 0xf, 0xf, true));
    p += i_as_f(__builtin_amdgcn_update_dpp(0, f_as_i(p), 0x118, 0xf, 0xf, true));
    p += i_as_f(__builtin_amdgcn_update_dpp(0, f_as_i(p), 0x142, 0xa, 0xf, true));
    p += i_as_f(__builtin_amdgcn_update_dpp(0, f_as_i(p), 0x143, 0xc, 0xf, true));
    return i_as_f(__builtin_amdgcn_readlane(f_as_i(p), 63));
}

// ===========================================================================
// convertK2: all input conversions in one launch (unchanged).
// ===========================================================================
__global__ __launch_bounds__(256) void convertK2(
    const float* __restrict__ o, const float* __restrict__ oW1,
    const float* __restrict__ eW1, const float* __restrict__ oW2,
    const float* __restrict__ eW2, const float* __restrict__ ob2,
    u16* __restrict__ o_bf, u16* __restrict__ bW1t, u16* __restrict__ bE1t,
    u16* __restrict__ o2bf, u16* __restrict__ w2th,
    u16* __restrict__ e1t20, float* __restrict__ biasp)
{
    __shared__ float tl[64][65];
    const int bid = blockIdx.x, t = threadIdx.x;

    if (bid < 512) {
        for (int it = 0; it < 6; ++it) {
            const int idx = (bid * 256 + t) + it * 131072;
            const int row = idx / 768, g = idx - row * 768;
            float4 v = make_float4(0.f, 0.f, 0.f, 0.f);
            if (g < 765) v = *(const float4*)(o + (size_t)row * 3060 + g * 4);
            const float* vp = (const float*)&v;
            ushort4 uh;
            uh.x = f2bf(vp[0]); uh.y = f2bf(vp[1]);
            uh.z = f2bf(vp[2]); uh.w = f2bf(vp[3]);
            *(ushort4*)(o_bf + (size_t)row * 3072 + g * 4) = uh;
        }
    } else if (bid < 1536) {
        const bool isW1 = (bid < 1280);
        const int idx = isW1 ? (bid - 512) : (bid - 1280);
        const int k0 = (idx >> 4) * 64, n0 = (idx & 15) * 64;
        const float* src = isW1 ? oW1 : (eW1 + (size_t)DIN * H_);
        const int Ksrc = isW1 ? 3060 : 1024;
        u16* dst = isW1 ? bW1t : bE1t;
        const int ldk = isW1 ? 3072 : 1024;
#pragma unroll
        for (int r = 0; r < 4; ++r) {
            const int k = k0 + r * 16 + (t >> 4);
            float4 v = make_float4(0.f, 0.f, 0.f, 0.f);
            if (k < Ksrc)
                v = *(const float4*)(src + (size_t)k * 1024 + n0 + (t & 15) * 4);
            const float* vp = (const float*)&v;
#pragma unroll
            for (int j = 0; j < 4; ++j)
                tl[r * 16 + (t >> 4)][(t & 15) * 4 + j] = vp[j];
        }
        __syncthreads();
#pragma unroll
        for (int r = 0; r < 4; ++r) {
            const int n = r * 16 + (t >> 4);
            ushort4 u;
            u.x = f2bf(tl[(t & 15) * 4 + 0][n]);
            u.y = f2bf(tl[(t & 15) * 4 + 1][n]);
            u.z = f2bf(tl[(t & 15) * 4 + 2][n]);
            u.w = f2bf(tl[(t & 15) * 4 + 3][n]);
            *(ushort4*)(dst + (size_t)(n0 + n) * ldk + k0 + (t & 15) * 4) = u;
        }
    } else if (bid < 1664) {
        const int base = (bid - 1536) * 256 + t;
#pragma unroll
        for (int it = 0; it < 8; ++it) {
            const int g = base + it * 32768;
            float4 v = *(const float4*)(oW2 + (size_t)g * 4);
            const float* vp = (const float*)&v;
            ushort4 uh;
            uh.x = f2bf(vp[0]); uh.y = f2bf(vp[1]);
            uh.z = f2bf(vp[2]); uh.w = f2bf(vp[3]);
            *(ushort4*)(o2bf + (size_t)g * 4) = uh;
        }
    } else if (bid < 1696) {
        const int c = bid - 1664;
#pragma unroll
        for (int kk = 0; kk < 4; ++kk) {
            const int k = kk * 256 + t;
            const float v = (c < C_) ? eW2[(size_t)k * C_ + c] : 0.f;
            w2th[(size_t)c * 1024 + k] = f2bf(v);
        }
    } else if (bid < 1700) {
        const int n = (bid - 1696) * 256 + t;
        u16 buf[32];
#pragma unroll
        for (int k = 0; k < 32; ++k)
            buf[k] = (k < DIN) ? f2bf(eW1[(size_t)k * H_ + n]) : (u16)0;
#pragma unroll
        for (int q = 0; q < 4; ++q)
            *(uint4*)(e1t20 + (size_t)n * 32 + q * 8) = *(uint4*)&buf[q * 8];
    } else {
        const int r = bid - 1700, kc = r >> 2, nb = r & 3;
        const int n = nb * 256 + t;
        const int k0 = kc * 128;
        float acc = 0.f;
#pragma unroll 8
        for (int k = 0; k < 128; ++k)
            acc = fmaf(ob2[k0 + k], eW1[(size_t)(DIN + k0 + k) * H_ + n], acc);
        biasp[kc * H_ + n] = acc;
    }
}

// ---------------------------------------------------------------------------
// MFMA GEMM tile (single bf16 A): C[gm0+128, gn0+64] = A @ Bt^T (+bias).
// ---------------------------------------------------------------------------
template <int BN>
__device__ __forceinline__ void gemm_mfma_tile(
    const u16* __restrict__ A0, const u16* __restrict__ Bt,
    float* __restrict__ C, const float* __restrict__ bias,
    int ldK, int nk1, int gm0, int gn0, char* lds)
{
    constexpr int FN    = BN / 32;
    constexpr int WNw   = BN / 2;
    constexpr int BR    = BN / 64;
    constexpr int BUFSZ = 8192 + BN * 64;

    const int tid  = threadIdx.x;
    const int wave = tid >> 6, l = tid & 63, ml = l & 15, koct = l >> 4;
    const int wm = wave >> 1, wn = wave & 1;
    const int swz = koct ^ ((ml >> 1) & 3);
    const int a_ro = (wm * 64 + ml) * 64 + swz * 16;
    const int b_ro = (wn * WNw + ml) * 64 + swz * 16;

    const int sm = tid >> 2, sq = tid & 3;
    int wAo[2], wBo[BR];
    size_t gAo[2], gBo[BR];
#pragma unroll
    for (int q = 0; q < 2; ++q) {
        const int m = q * 64 + sm;
        wAo[q] = m * 64 + ((sq ^ ((m >> 1) & 3)) * 16);
        gAo[q] = (size_t)(gm0 + m) * ldK * 2 + sq * 16;
    }
#pragma unroll
    for (int q = 0; q < BR; ++q) {
        const int n = q * 64 + sm;
        wBo[q] = n * 64 + ((sq ^ ((n >> 1) & 3)) * 16);
        gBo[q] = (size_t)(gn0 + n) * ldK * 2 + sq * 16;
    }

    f32x4 acc[4][FN];
    const f32x4 zz = {0.f, 0.f, 0.f, 0.f};
#pragma unroll
    for (int i = 0; i < 4; ++i)
#pragma unroll
        for (int j = 0; j < FN; ++j) acc[i][j] = zz;

    const char* A0c = (const char*)A0;
    const char* Btc = (const char*)Bt;

    uint4 st[2 + BR];
    auto stage = [&](int kt) {
        const size_t koff = (size_t)kt * 64;
        st[0] = *(const uint4*)(A0c + gAo[0] + koff);
        st[1] = *(const uint4*)(A0c + gAo[1] + koff);
#pragma unroll
        for (int q = 0; q < BR; ++q)
            st[2 + q] = *(const uint4*)(Btc + gBo[q] + koff);
    };
    auto dswrite = [&](int buf) {
        char* d = lds + buf * BUFSZ;
        *(uint4*)(d + wAo[0]) = st[0];
        *(uint4*)(d + wAo[1]) = st[1];
#pragma unroll
        for (int q = 0; q < BR; ++q)
            *(uint4*)(d + 8192 + wBo[q]) = st[2 + q];
    };
    auto compute = [&](int buf) {
        const char* As = lds + buf * BUFSZ;
        const char* Bs = As + 8192;
        bf16x8 af[4], bfv[FN];
#pragma unroll
        for (int fm = 0; fm < 4; ++fm)
            af[fm] = *(const bf16x8*)(As + a_ro + fm * 1024);
#pragma unroll
        for (int fn = 0; fn < FN; ++fn)
            bfv[fn] = *(const bf16x8*)(Bs + b_ro + fn * 1024);
#pragma unroll
        for (int fm = 0; fm < 4; ++fm)
#pragma unroll
            for (int fn = 0; fn < FN; ++fn)
                acc[fm][fn] = __builtin_amdgcn_mfma_f32_16x16x32_bf16(
                    af[fm], bfv[fn], acc[fm][fn], 0, 0, 0);
    };

    stage(0); dswrite(0); __syncthreads();
    for (int kt = 0; kt < nk1; ++kt) {
        if (kt + 1 < nk1) stage(kt + 1);
        compute(kt & 1);
        if (kt + 1 < nk1) dswrite((kt + 1) & 1);
        __syncthreads();
    }

    float br[FN];
#pragma unroll
    for (int fn = 0; fn < FN; ++fn)
        br[fn] = bias ? bias[gn0 + wn * WNw + fn * 16 + ml] : 0.f;
#pragma unroll
    for (int fm = 0; fm < 4; ++fm) {
        const int rowb = gm0 + wm * 64 + fm * 16 + koct * 4;
#pragma unroll
        for (int fn = 0; fn < FN; ++fn) {
            const int col = gn0 + wn * WNw + fn * 16 + ml;
#pragma unroll
            for (int r = 0; r < 4; ++r)
                C[(size_t)(rowb + r) * 1024 + col] = acc[fm][fn][r] + br[fn];
        }
    }
}

// kernelA2: [0,384) GEMM1 split-K3 -> p_h1[c]; [384,512) Wc -> p_wc
__global__ __launch_bounds__(256) void kernelA2(
    const u16* __restrict__ o_bf, const u16* __restrict__ bW1t,
    const u16* __restrict__ o2bf, const u16* __restrict__ bE1t,
    float* __restrict__ p_h1, float* __restrict__ p_wc)
{
    __shared__ alignas(16) char lds[2 * 12288];
    const int bid = blockIdx.x;
    if (bid < 384) {
        const int c = bid >> 7, tl = bid & 127;
        gemm_mfma_tile<64>(o_bf + c * 1024, bW1t + c * 1024,
                           p_h1 + (size_t)c * 1048576, nullptr, 3072, 32,
                           (tl >> 4) * 128, (tl & 15) * 64, lds);
    } else {
        const int tl = bid - 384;
        gemm_mfma_tile<64>(o2bf, bE1t, p_wc, nullptr, 1024, 32,
                           (tl >> 4) * 128, (tl & 15) * 64, lds);
    }
}

// epilogue2: [0,256) h1bf; [256,512) Wct = bf16(p_wc^T); [512] biasWc sum
__global__ __launch_bounds__(256) void epilogue2(
    const float* __restrict__ p_h1, const float* __restrict__ p_wc,
    const float* __restrict__ ob1, const float* __restrict__ eb1,
    const float* __restrict__ biasp,
    u16* __restrict__ h1bf, u16* __restrict__ Wct, float* __restrict__ biasWc)
{
    __shared__ float tl[64][65];
    const int bid = blockIdx.x, t = threadIdx.x;
    if (bid < 256) {
#pragma unroll
        for (int it = 0; it < 4; ++it) {
            const int g = bid * 1024 + it * 256 + t;
            const size_t e = (size_t)g * 4;
            float4 a = *(const float4*)(p_h1 + e);
            float4 b = *(const float4*)(p_h1 + 1048576 + e);
            float4 c = *(const float4*)(p_h1 + 2097152 + e);
            float4 s = *(const float4*)(ob1 + (e & 1023));
            const float *ap = (const float*)&a, *bp = (const float*)&b,
                        *cp = (const float*)&c, *sp = (const float*)&s;
            ushort4 uh;
            u16* up = (u16*)&uh;
#pragma unroll
            for (int j = 0; j < 4; ++j)
                up[j] = f2bf(fmaxf(ap[j] + bp[j] + cp[j] + sp[j], 0.f));
            *(ushort4*)(h1bf + e) = uh;
        }
    } else if (bid < 512) {
        const int idx = bid - 256;
        const int k0 = (idx >> 4) * 64, n0 = (idx & 15) * 64;
#pragma unroll
        for (int r = 0; r < 4; ++r) {
            const int k = k0 + r * 16 + (t >> 4);
            float4 v = *(const float4*)(p_wc + (size_t)k * 1024 + n0 + (t & 15) * 4);
            const float* vp = (const float*)&v;
#pragma unroll
            for (int j = 0; j < 4; ++j)
                tl[r * 16 + (t >> 4)][(t & 15) * 4 + j] = vp[j];
        }
        __syncthreads();
#pragma unroll
        for (int r = 0; r < 4; ++r) {
            const int n = r * 16 + (t >> 4);
            ushort4 u;
            u.x = f2bf(tl[(t & 15) * 4 + 0][n]);
            u.y = f2bf(tl[(t & 15) * 4 + 1][n]);
            u.z = f2bf(tl[(t & 15) * 4 + 2][n]);
            u.w = f2bf(tl[(t & 15) * 4 + 3][n]);
            *(ushort4*)(Wct + (size_t)(n0 + n) * 1024 + k0 + (t & 15) * 4) = u;
        }
    } else {
        const int j0 = t * 4;
        float4 s = *(const float4*)(eb1 + j0);
        float* sp = (float*)&s;
#pragma unroll
        for (int kc = 0; kc < 8; ++kc) {
            float4 p = *(const float4*)(biasp + kc * H_ + j0);
            const float* pp = (const float*)&p;
#pragma unroll
            for (int i = 0; i < 4; ++i) sp[i] += pp[i];
        }
        *(float4*)(biasWc + j0) = s;
    }
}

// kernelB2 split-K2
__global__ __launch_bounds__(256) void kernelB2(
    const u16* __restrict__ h1bf, const u16* __restrict__ Wct,
    const float* __restrict__ biasWc,
    float* __restrict__ base0, float* __restrict__ base1)
{
    __shared__ alignas(16) char lds[2 * 12288];
    const int bid = blockIdx.x;
    const int p = bid >> 7, tl = bid & 127;
    gemm_mfma_tile<64>(h1bf + p * 512, Wct + p * 512,
                       p ? base1 : base0, p ? biasWc : nullptr,
                       1024, 16, (tl >> 4) * 128, (tl & 15) * 64, lds);
}

// ===========================================================================
// Phase 1 (v7): v6 structure with the VGPR cap LIFTED (launch_bounds(256,2)).
// R10's ereg preload + consumer arrays spilled to scratch at the (256,4)
// 64-VGPR cap (VGPR_Count=64, FETCH 74MB). With cap 256 everything stays in
// registers: produce = pure MFMA+VALU; consume = 2x ds_read_b128 + FMA + DPP.
// ===========================================================================
#define CPH6  16
#define CNPH6 6        // 6*16 = 96 >= 83
#define ASTR  1048     // u16 row stride (2096 B, 16B-aligned)
#define APL   528      // u16 plane stride (1056 B, 16B-aligned)

__global__ __launch_bounds__(256, 2) void chain_seq7(
    const float* __restrict__ x, const u16* __restrict__ e1t20,
    const float* __restrict__ eW1, const float* __restrict__ eW2,
    const float* __restrict__ eb2,
    const float* __restrict__ base0, const float* __restrict__ base1,
    float* __restrict__ cur0_buf)
{
    __shared__ alignas(16) u16 A_bf[CPH6 * ASTR];   // 33,536 B
    __shared__ float xl[T_ * DIN];                  // 6,800 B

    const int b = blockIdx.x, tid = threadIdx.x;
    const int w = tid >> 6, l = tid & 63;
    const int ml = l & 15, koct = l >> 4;

    for (int i = tid; i < T_ * DIN; i += 256)
        xl[i] = x[(size_t)b * (T_ * DIN) + i];

    const f32x4 zz = {0.f, 0.f, 0.f, 0.f};

    // ---- producer registers: e1t20 slice (static-indexed, fully unrolled) --
    bf16x8 ereg[22];
    if (w) {
#pragma unroll
        for (int q = 0; q < 22; ++q) {
            const int jt = (w - 1) + 3 * q;
            if (jt < 64)
                ereg[q] = *(const bf16x8*)
                    &e1t20[(size_t)(jt * 16 + ml) * 32 + koct * 8];
        }
    }

    // ---- consumer registers ----
    float u[16], v[16], baseR[16];
    float prev = 0.f, cur0_init = 0.f;
    if (w == 0) {
        const int j0 = l * 16;
#pragma unroll
        for (int i = 0; i < 16; i += 4)
            *(float4*)&u[i] = *(const float4*)&eW1[j0 + i];
#pragma unroll
        for (int i = 0; i < 16; ++i)
            v[i] = eW2[(size_t)(j0 + i) * C_];
#pragma unroll
        for (int i = 0; i < 16; i += 4) {
            float4 b0v = *(const float4*)&base0[(size_t)b * H_ + j0 + i];
            float4 b1v = *(const float4*)&base1[(size_t)b * H_ + j0 + i];
            baseR[i + 0] = b0v.x + b1v.x;
            baseR[i + 1] = b0v.y + b1v.y;
            baseR[i + 2] = b0v.z + b1v.z;
            baseR[i + 3] = b0v.w + b1v.w;
        }
        cur0_init = x[(size_t)b * (T_ * DIN)];
    }
    __syncthreads();   // xl ready

    const float eb20 = eb2[0];
    float* cb = cur0_buf + (size_t)b * TOUT;
    int t = 0;

#pragma unroll 1
    for (int ph = 0; ph < CNPH6; ++ph) {
        const int t0 = ph * CPH6;

        // ---- produce phase ph (waves 1-3; pure MFMA+VALU, no memory) ----
        if (w) {
            u16 hw[8];
            const int tg = t0 + ml;
#pragma unroll
            for (int e = 0; e < 8; ++e) {
                const int k = koct * 8 + e;
                float vx = 0.f;
                if (k >= 1 && k < DIN && tg < T_) vx = xl[tg * DIN + k];
                hw[e] = f2bf(vx);
            }
            bf16x8 af;
            {
                uint4 pk;
                pk.x = hw[0] | ((unsigned)hw[1] << 16);
                pk.y = hw[2] | ((unsigned)hw[3] << 16);
                pk.z = hw[4] | ((unsigned)hw[5] << 16);
                pk.w = hw[6] | ((unsigned)hw[7] << 16);
                af = *(bf16x8*)&pk;
            }
            const int wbase = (ml >> 3) * APL + (ml & 7);
#pragma unroll
            for (int q = 0; q < 22; ++q) {
                const int jt = (w - 1) + 3 * q;
                if (jt < 64) {
                    f32x4 c = __builtin_amdgcn_mfma_f32_16x16x32_bf16(
                        af, ereg[q], zz, 0, 0, 0);
#pragma unroll
                    for (int r = 0; r < 4; ++r) {
                        const int row = koct * 4 + r;
                        A_bf[row * ASTR + wbase + jt * 8] = f2bf(c[r]);
                    }
                }
            }
        }
        __syncthreads();   // A ready

        // ---- consume (wave 0): serial steps ----
        if (w == 0) {
            const int rem = 83 - t0;
            const int nst = (rem < CPH6) ? rem : CPH6;

            uint4 ra = *(const uint4*)&A_bf[l * 8];
            uint4 rb = *(const uint4*)&A_bf[APL + l * 8];
            float ab[16];
            {
                const u16* pa = (const u16*)&ra;
                const u16* pb = (const u16*)&rb;
#pragma unroll
                for (int i = 0; i < 8; ++i) {
                    ab[i]     = bf2f(pa[i]) + baseR[i];
                    ab[8 + i] = bf2f(pb[i]) + baseR[8 + i];
                }
            }

            for (int sl = 0; sl < nst; ++sl, ++t) {
                const int sln = (sl + 1 < nst) ? sl + 1 : sl;
                uint4 rna = *(const uint4*)&A_bf[sln * ASTR + l * 8];
                uint4 rnb = *(const uint4*)&A_bf[sln * ASTR + APL + l * 8];

                const float cur0 = (t == 0) ? cur0_init : prev;
                if (l == 0) cb[t] = cur0;

                float p0 = 0.f, p1 = 0.f, p2 = 0.f, p3 = 0.f;
#pragma unroll
                for (int i = 0; i < 16; i += 4) {
                    p0 = fmaf(fmaxf(fmaf(cur0, u[i + 0], ab[i + 0]), 0.f), v[i + 0], p0);
                    p1 = fmaf(fmaxf(fmaf(cur0, u[i + 1], ab[i + 1]), 0.f), v[i + 1], p1);
                    p2 = fmaf(fmaxf(fmaf(cur0, u[i + 2], ab[i + 2]), 0.f), v[i + 2], p2);
                    p3 = fmaf(fmaxf(fmaf(cur0, u[i + 3], ab[i + 3]), 0.f), v[i + 3], p3);
                }
                prev = eb20 + wave64_sum_bcast((p0 + p1) + (p2 + p3));

                {   // convert prefetched next row (off the dependent chain)
                    const u16* pa = (const u16*)&rna;
                    const u16* pb = (const u16*)&rnb;
#pragma unroll
                    for (int i = 0; i < 8; ++i) {
                        ab[i]     = bf2f(pa[i]) + baseR[i];
                        ab[8 + i] = bf2f(pb[i]) + baseR[8 + i];
                    }
                }
            }
        }
        __syncthreads();   // consumer done with A before next produce
    }
    if (w == 0 && l == 0) cb[TOUT - 1] = prev;
}

// ===========================================================================
// Phase 2: parallel expansion (unchanged).
// ===========================================================================
__global__ __launch_bounds__(256, 4) void expand(
    const float* __restrict__ x, const float* __restrict__ base0,
    const float* __restrict__ base1, const float* __restrict__ cur0_buf,
    const u16* __restrict__ e1t20, const u16* __restrict__ w2th,
    const float* __restrict__ eb2, float* __restrict__ out)
{
    __shared__ u16 A_lds[64 * 32];
    __shared__ u16 e_lds[128 * 32];
    __shared__ u16 h_lds[64 * 128];
    __shared__ u16 w2_s[32 * 128];
    __shared__ float base_s[2 * 128];

    const int tid = threadIdx.x;
    const int g0 = blockIdx.x * 64;
    const int w = tid >> 6, l = tid & 63, ml = l & 15, koct = l >> 4;
    const int b0 = g0 / 84;
    const int b1 = (b0 + 1 < B_) ? b0 + 1 : b0;

    {
        const int row = tid >> 2, q = tid & 3;
        const int g = g0 + row, bb = g / 84, tt = g - bb * 84;
        u16 hw[8];
#pragma unroll
        for (int c = 0; c < 8; ++c) {
            const int k = q * 8 + c;
            float v = 0.f;
            if (k == 0) v = cur0_buf[g];
            else if (k < DIN) v = x[(size_t)bb * (T_ * DIN) + tt * DIN + k];
            hw[c] = f2bf(v);
        }
        uint4 pk;
        pk.x = hw[0] | ((unsigned)hw[1] << 16);
        pk.y = hw[2] | ((unsigned)hw[3] << 16);
        pk.z = hw[4] | ((unsigned)hw[5] << 16);
        pk.w = hw[6] | ((unsigned)hw[7] << 16);
        *(uint4*)&A_lds[row * 32 + q * 8] = pk;
    }

    const int grow = w * 16 + ml;
    const int g = g0 + grow;
    const int sel = g / 84 - b0;
    __syncthreads();
    const bf16x8 xfrag = *(const bf16x8*)&A_lds[grow * 32 + koct * 8];

    f32x4 acc[2];
    const f32x4 zz = {0.f, 0.f, 0.f, 0.f};
    acc[0] = zz; acc[1] = zz;

#pragma unroll 1
    for (int kc = 0; kc < 8; ++kc) {
        const int n0 = kc * 128;
        if (kc) __syncthreads();
        {
            const u16* src = e1t20 + n0 * 32 + tid * 16;
            *(uint4*)&e_lds[tid * 16]     = *(const uint4*)src;
            *(uint4*)&e_lds[tid * 16 + 8] = *(const uint4*)(src + 8);
        }
        {
            const int wr = tid >> 3, sg = tid & 7;
            const u16* srcw = w2th + (size_t)wr * 1024 + n0 + sg * 16;
            const int s0 = (sg * 2) ^ (wr & 15), s1 = (sg * 2 + 1) ^ (wr & 15);
            *(uint4*)&w2_s[wr * 128 + s0 * 8] = *(const uint4*)srcw;
            *(uint4*)&w2_s[wr * 128 + s1 * 8] = *(const uint4*)(srcw + 8);
        }
        {
            const int bs = tid >> 7, c = tid & 127;
            const size_t rb = (size_t)(bs ? b1 : b0) * H_ + n0 + c;
            base_s[bs * 128 + c] = base0[rb] + base1[rb];
        }
        __syncthreads();

#pragma unroll
        for (int p = 0; p < 8; ++p) {
            const bf16x8 ef = *(const bf16x8*)&e_lds[(p * 16 + ml) * 32 + koct * 8];
            f32x4 c1 = zz;
            c1 = __builtin_amdgcn_mfma_f32_16x16x32_bf16(ef, xfrag, c1, 0, 0, 0);
            u16 hq[4];
#pragma unroll
            for (int q = 0; q < 4; ++q) {
                const int j = p * 16 + koct * 4 + q;
                const float v = c1[q] + base_s[sel * 128 + j];
                hq[q] = f2bf(fmaxf(v, 0.f));
            }
            uint2 pk;
            pk.x = hq[0] | ((unsigned)hq[1] << 16);
            pk.y = hq[2] | ((unsigned)hq[3] << 16);
            const int s16 = (p * 2 + (koct >> 1)) ^ ml;
            *(uint2*)&h_lds[grow * 128 + s16 * 8 + (koct & 1) * 4] = pk;
        }

#pragma unroll
        for (int ks = 0; ks < 4; ++ks) {
            const int sl = (((ks * 4 + koct) ^ ml)) * 8;
            const bf16x8 hf = *(const bf16x8*)&h_lds[grow * 128 + sl];
#pragma unroll
            for (int ct = 0; ct < 2; ++ct) {
                const bf16x8 wf = *(const bf16x8*)&w2_s[(ct * 16 + ml) * 128 + sl];
                acc[ct] = __builtin_amdgcn_mfma_f32_16x16x32_bf16(
                    wf, hf, acc[ct], 0, 0, 0);
            }
        }
    }

#pragma unroll
    for (int ct = 0; ct < 2; ++ct) {
#pragma unroll
        for (int q = 0; q < 4; ++q) {
            const int c = ct * 16 + koct * 4 + q;
            if (c < C_)
                out[(size_t)g * C_ + c] = acc[ct][q] + eb2[c];
        }
    }
}

// ===========================================================================
// FALLBACK fp32 path — used only if ws is too small.
// ===========================================================================
struct GemmSmem {
    float As[2][16][68];
    float Bs[2][16][64];
};

template <int RELU>
__device__ __forceinline__ void gemm_core(
    const float* __restrict__ A, int lda,
    const float* __restrict__ Bm, int ldb,
    const float* __restrict__ bias, const float* __restrict__ bias_parts,
    float* __restrict__ Cc, int ldc, int K, int tile, GemmSmem& sm)
{
    const int tid = threadIdx.x;
    const int bm = (tile >> 4) * 64, bn = (tile & 15) * 64;
    const int wave = tid >> 6, l = tid & 63;
    const int n0 = (wave & 1) * 32 + (l & 7) * 4;
    const int m0 = (wave >> 1) * 32 + (l >> 3) * 4;
    const int am = tid >> 2, akq = tid & 3;
    const int bk = tid >> 4, bnq = tid & 15;
    const float* Arow = A + (size_t)(bm + am) * lda + akq * 4;
    const float* Brow = Bm + (size_t)bk * ldb + bn + bnq * 4;
    float acc[4][4] = {};
    const int nIter = (K + 15) >> 4;
    {
        const int ak = akq * 4;
        float4 av = (ak + 4 <= K) ? *(const float4*)(Arow)
                                  : make_float4(0.f, 0.f, 0.f, 0.f);
        float4 bv = (bk < K) ? *(const float4*)(Brow)
                             : make_float4(0.f, 0.f, 0.f, 0.f);
        sm.As[0][akq * 4 + 0][am] = av.x; sm.As[0][akq * 4 + 1][am] = av.y;
        sm.As[0][akq * 4 + 2][am] = av.z; sm.As[0][akq * 4 + 3][am] = av.w;
        *(float4*)&sm.Bs[0][bk][bnq * 4] = bv;
    }
    __syncthreads();
    for (int it = 0; it < nIter; ++it) {
        const int cur = it & 1;
        const bool pf = (it + 1 < nIter);
        float4 pav, pbv;
        if (pf) {
            const int k0 = (it + 1) << 4, ak = k0 + akq * 4;
            pav = (ak + 4 <= K) ? *(const float4*)(Arow + k0)
                                : make_float4(0.f, 0.f, 0.f, 0.f);
            pbv = (k0 + bk < K) ? *(const float4*)(Brow + (size_t)k0 * ldb)
                                : make_float4(0.f, 0.f, 0.f, 0.f);
        }
#pragma unroll
        for (int kk = 0; kk < 16; ++kk) {
            float ar[4], br[4];
            *(float4*)ar = *(const float4*)&sm.As[cur][kk][m0];
            *(float4*)br = *(const float4*)&sm.Bs[cur][kk][n0];
#pragma unroll
            for (int r = 0; r < 4; ++r)
#pragma unroll
                for (int c = 0; c < 4; ++c)
                    acc[r][c] = fmaf(ar[r], br[c], acc[r][c]);
        }
        if (pf) {
            const int nb = cur ^ 1;
            sm.As[nb][akq * 4 + 0][am] = pav.x; sm.As[nb][akq * 4 + 1][am] = pav.y;
            sm.As[nb][akq * 4 + 2][am] = pav.z; sm.As[nb][akq * 4 + 3][am] = pav.w;
            *(float4*)&sm.Bs[nb][bk][bnq * 4] = pbv;
        }
        __syncthreads();
    }
    float bias4[4];
#pragma unroll
    for (int c = 0; c < 4; ++c) {
        const int col = bn + n0 + c;
        float b = bias ? bias[col] : 0.f;
        if (bias_parts)
#pragma unroll
            for (int p = 0; p < 8; ++p) b += bias_parts[p * H_ + col];
        bias4[c] = b;
    }
#pragma unroll
    for (int r = 0; r < 4; ++r) {
        float4 v; float* vp = (float*)&v;
#pragma unroll
        for (int c = 0; c < 4; ++c) {
            float t2 = acc[r][c] + bias4[c];
            if (RELU) t2 = fmaxf(t2, 0.f);
            vp[c] = t2;
        }
        *(float4*)&Cc[(size_t)(bm + m0 + r) * ldc + bn + n0] = v;
    }
}

__global__ __launch_bounds__(256) void kernelA_fb(
    const float* __restrict__ o, const float* __restrict__ oW1,
    const float* __restrict__ ob1, const float* __restrict__ oW2,
    const float* __restrict__ eW1, const float* __restrict__ ob2,
    float* __restrict__ h1, float* __restrict__ Wc, float* __restrict__ biasc)
{
    __shared__ GemmSmem sm;
    const int bid = blockIdx.x;
    if (bid < 256) {
        gemm_core<1>(o, OBJ_, oW1, H_, ob1, nullptr, h1, H_, OBJ_, bid, sm);
    } else if (bid < 512) {
        gemm_core<0>(oW2, H_, eW1 + (size_t)DIN * H_, H_, nullptr, nullptr,
                     Wc, H_, H_, bid - 256, sm);
    } else {
        const int r = bid - 512, kc = r >> 2, nb = r & 3;
        const int n = nb * 256 + (int)threadIdx.x;
        const int k0 = kc * 128;
        float acc = 0.f;
#pragma unroll 8
        for (int k = 0; k < 128; ++k)
            acc = fmaf(ob2[k0 + k], eW1[(size_t)(DIN + k0 + k) * H_ + n], acc);
        biasc[kc * H_ + n] = acc;
    }
}

__global__ __launch_bounds__(256) void kernelB_fb(
    const float* __restrict__ h1, const float* __restrict__ Wc,
    const float* __restrict__ eb1, const float* __restrict__ biasc,
    float* __restrict__ base0)
{
    __shared__ GemmSmem sm;
    gemm_core<0>(h1, H_, Wc, H_, eb1, biasc, base0, H_, H_, blockIdx.x, sm);
}

__global__ __launch_bounds__(256, 2) void expert_seq_fb(
    const float* __restrict__ x, const float* __restrict__ eW1,
    const float* __restrict__ eW2, const float* __restrict__ eb2,
    const float* __restrict__ base0, float* __restrict__ out)
{
    const int b   = blockIdx.x;
    const int tid = threadIdx.x;
    const int j0  = tid * 4;

    __shared__ float xl[T_ * DIN];
    __shared__ float pl[256 * 29];
    __shared__ float pl2[256];
    __shared__ float prevs;

    for (int idx = tid; idx < T_ * DIN; idx += 256)
        xl[idx] = x[(size_t)b * (T_ * DIN) + idx];

    float w1r[DIN][4];
#pragma unroll
    for (int d = 0; d < DIN; ++d)
        *(float4*)w1r[d] = *(const float4*)&eW1[(size_t)d * H_ + j0];

    float base_r[4];
    *(float4*)base_r = *(const float4*)&base0[(size_t)b * H_ + j0];

    float w2r[4][C_];
#pragma unroll
    for (int i = 0; i < 4; ++i)
#pragma unroll
        for (int c = 0; c < C_; ++c)
            w2r[i][c] = eW2[(size_t)(j0 + i) * C_ + c];

    const float myb = (tid < C_) ? eb2[tid] : 0.f;
    __syncthreads();

    float prev = 0.f;
#pragma unroll 1
    for (int t = 0; t < TOUT; ++t) {
        const float cur0 = (t == 0) ? xl[0] : prev;
        float h[4];
#pragma unroll
        for (int i = 0; i < 4; ++i)
            h[i] = fmaf(cur0, w1r[0][i], base_r[i]);
#pragma unroll
        for (int d = 1; d < DIN; ++d) {
            const float xv = xl[t * DIN + d];
#pragma unroll
            for (int i = 0; i < 4; ++i)
                h[i] = fmaf(xv, w1r[d][i], h[i]);
        }
#pragma unroll
        for (int i = 0; i < 4; ++i)
            h[i] = fmaxf(h[i], 0.f);
        float p[C_];
#pragma unroll
        for (int c = 0; c < C_; ++c)
            p[c] = h[0] * w2r[0][c];
#pragma unroll
        for (int i = 1; i < 4; ++i)
#pragma unroll
            for (int c = 0; c < C_; ++c)
                p[c] = fmaf(h[i], w2r[i][c], p[c]);
#pragma unroll
        for (int c = 0; c < C_; ++c)
            pl[tid * 29 + c] = p[c];
        __syncthreads();
        {
            const int c2 = tid & 31, grp = tid >> 5;
            float s = 0.f;
            if (c2 < C_) {
                const int basei = grp * 32 * 29 + c2;
#pragma unroll
                for (int s2 = 0; s2 < 32; ++s2)
                    s += pl[basei + s2 * 29];
            }
            pl2[tid] = s;
        }
        __syncthreads();
        if (tid < C_) {
            float o = myb;
#pragma unroll
            for (int g = 0; g < 8; ++g)
                o += pl2[g * 32 + tid];
            out[((size_t)b * TOUT + t) * C_ + tid] = o;
            if (tid == 0) prevs = o;
        }
        __syncthreads();
        prev = prevs;
    }
}

// ===========================================================================
extern "C" void kernel_launch(void* const* d_in, const int* in_sizes, int n_in,
                              void* d_out, int out_size, void* d_ws, size_t ws_size,
                              hipStream_t stream)
{
    const float* o   = (const float*)d_in[0];
    const float* x   = (const float*)d_in[1];
    const float* oW1 = (const float*)d_in[2];
    const float* ob1 = (const float*)d_in[3];
    const float* oW2 = (const float*)d_in[4];
    const float* ob2 = (const float*)d_in[5];
    const float* eW1 = (const float*)d_in[6];
    const float* eb1 = (const float*)d_in[7];
    const float* eW2 = (const float*)d_in[8];
    const float* eb2 = (const float*)d_in[9];

    float* outp = (float*)d_out;
    float* ws   = (float*)d_ws;
    dim3 blk(256);

    const size_t NEED2 = 38326272;
    if (ws_size >= NEED2) {
        float* p_h1   = ws;                       // 3*1048576 f
        float* p_wc   = ws + 3145728;             // 1048576 f
        float* biasWc = ws + 4194304;             // 1024 f
        float* cur0b  = ws + 4195328;             // 86016 f
        float* biasp  = ws + 4281344;             // 8192 f
        u16*   ub     = (u16*)(ws + 4289536);
        u16 *o_bf  = ub,             *bW1t = ub + 3145728;
        u16 *bE1t  = ub + 6291456,   *o2bf = ub + 7340032;
        u16 *h1bf  = ub + 8388608,   *Wct  = ub + 9437184;
        u16 *w2th  = ub + 10485760;
        u16 *e1t20 = ub + 10551296;
        float* base0 = p_h1;          // reuse p_h1 after epilogue2 consumed it
        float* base1 = p_h1 + 1048576;

        convertK2<<<dim3(1732), blk, 0, stream>>>(o, oW1, eW1, oW2, eW2, ob2,
                                                  o_bf, bW1t, bE1t, o2bf,
                                                  w2th, e1t20, biasp);
        kernelA2<<<dim3(512), blk, 0, stream>>>(o_bf, bW1t, o2bf, bE1t,
                                                p_h1, p_wc);
        epilogue2<<<dim3(513), blk, 0, stream>>>(p_h1, p_wc, ob1, eb1, biasp,
                                                 h1bf, Wct, biasWc);
        kernelB2<<<dim3(256), blk, 0, stream>>>(h1bf, Wct, biasWc,
                                                base0, base1);
        chain_seq7<<<dim3(B_), blk, 0, stream>>>(x, e1t20, eW1, eW2, eb2,
                                                 base0, base1, cur0b);
        expand<<<dim3(1344), blk, 0, stream>>>(x, base0, base1, cur0b, e1t20,
                                               w2th, eb2, outp);
    } else {
        const size_t MF = (size_t)H_ * H_;
        float* h1    = ws;
        float* Wc    = ws + MF;
        float* base0 = ws + 2 * MF;
        float* biasc = outp;
        kernelA_fb<<<dim3(544), blk, 0, stream>>>(o, oW1, ob1, oW2, eW1, ob2,
                                                  h1, Wc, biasc);
        kernelB_fb<<<dim3(256), blk, 0, stream>>>(h1, Wc, eb1, biasc, base0);
        expert_seq_fb<<<dim3(B_), blk, 0, stream>>>(x, eW1, eW2, eb2,
                                                    base0, outp);
    }
}

// Round 14
// 157.475 us; speedup vs baseline: 1.0013x; 1.0013x over previous
//
#include <hip/hip_runtime.h>
#include <hip/hip_bf16.h>

#define B_   1024
#define T_   85
#define DIN  20
#define H_   1024
#define C_   27
#define OBJ_ (T_ * 36)   // 3060
#define TOUT (T_ - 1)    // 84

typedef unsigned short u16;
typedef __attribute__((ext_vector_type(8))) short bf16x8;
typedef __attribute__((ext_vector_type(4))) float f32x4;

__device__ __forceinline__ u16 f2bf(float f) {
    __hip_bfloat16 h = __float2bfloat16(f);
    return *reinterpret_cast<u16*>(&h);
}
__device__ __forceinline__ float bf2f(u16 u) {
    __hip_bfloat16 h;
    *reinterpret_cast<u16*>(&h) = u;
    return __bfloat162float(h);
}
__device__ __forceinline__ int f_as_i(float f) {
    union { float f; int i; } u; u.f = f; return u.i;
}
__device__ __forceinline__ float i_as_f(int i) {
    union { float f; int i; } u; u.i = i; return u.f;
}

// 64-lane sum via DPP (VALU pipe): row_shr 1/2/4/8 + bcast15 + bcast31,
// total lands in lane 63; readlane broadcasts to all lanes.
__device__ __forceinline__ float wave64_sum_bcast(float p) {
    p += i_as_f(__builtin_amdgcn_update_dpp(0, f_as_i(p), 0x111, 0xf, 0xf, true));
    p += i_as_f(__builtin_amdgcn_update_dpp(0, f_as_i(p), 0x112, 0xf, 0xf, true));
    p += i_as_f(__builtin_amdgcn_update_dpp(0, f_as_i(p), 0x114, 0xf, 0xf, true));
    p += i_as_f(__builtin_amdgcn_update_dpp(0, f_as_i(p), 0x118, 0xf, 0xf, true));
    p += i_as_f(__builtin_amdgcn_update_dpp(0, f_as_i(p), 0x142, 0xa, 0xf, true));
    p += i_as_f(__builtin_amdgcn_update_dpp(0, f_as_i(p), 0x143, 0xc, 0xf, true));
    return i_as_f(__builtin_amdgcn_readlane(f_as_i(p), 63));
}

// ===========================================================================
// convertK2: all input conversions in one launch (unchanged).
// ===========================================================================
__global__ __launch_bounds__(256) void convertK2(
    const float* __restrict__ o, const float* __restrict__ oW1,
    const float* __restrict__ eW1, const float* __restrict__ oW2,
    const float* __restrict__ eW2, const float* __restrict__ ob2,
    u16* __restrict__ o_bf, u16* __restrict__ bW1t, u16* __restrict__ bE1t,
    u16* __restrict__ o2bf, u16* __restrict__ w2th,
    u16* __restrict__ e1t20, float* __restrict__ biasp)
{
    __shared__ float tl[64][65];
    const int bid = blockIdx.x, t = threadIdx.x;

    if (bid < 512) {
        for (int it = 0; it < 6; ++it) {
            const int idx = (bid * 256 + t) + it * 131072;
            const int row = idx / 768, g = idx - row * 768;
            float4 v = make_float4(0.f, 0.f, 0.f, 0.f);
            if (g < 765) v = *(const float4*)(o + (size_t)row * 3060 + g * 4);
            const float* vp = (const float*)&v;
            ushort4 uh;
            uh.x = f2bf(vp[0]); uh.y = f2bf(vp[1]);
            uh.z = f2bf(vp[2]); uh.w = f2bf(vp[3]);
            *(ushort4*)(o_bf + (size_t)row * 3072 + g * 4) = uh;
        }
    } else if (bid < 1536) {
        const bool isW1 = (bid < 1280);
        const int idx = isW1 ? (bid - 512) : (bid - 1280);
        const int k0 = (idx >> 4) * 64, n0 = (idx & 15) * 64;
        const float* src = isW1 ? oW1 : (eW1 + (size_t)DIN * H_);
        const int Ksrc = isW1 ? 3060 : 1024;
        u16* dst = isW1 ? bW1t : bE1t;
        const int ldk = isW1 ? 3072 : 1024;
#pragma unroll
        for (int r = 0; r < 4; ++r) {
            const int k = k0 + r * 16 + (t >> 4);
            float4 v = make_float4(0.f, 0.f, 0.f, 0.f);
            if (k < Ksrc)
                v = *(const float4*)(src + (size_t)k * 1024 + n0 + (t & 15) * 4);
            const float* vp = (const float*)&v;
#pragma unroll
            for (int j = 0; j < 4; ++j)
                tl[r * 16 + (t >> 4)][(t & 15) * 4 + j] = vp[j];
        }
        __syncthreads();
#pragma unroll
        for (int r = 0; r < 4; ++r) {
            const int n = r * 16 + (t >> 4);
            ushort4 u;
            u.x = f2bf(tl[(t & 15) * 4 + 0][n]);
            u.y = f2bf(tl[(t & 15) * 4 + 1][n]);
            u.z = f2bf(tl[(t & 15) * 4 + 2][n]);
            u.w = f2bf(tl[(t & 15) * 4 + 3][n]);
            *(ushort4*)(dst + (size_t)(n0 + n) * ldk + k0 + (t & 15) * 4) = u;
        }
    } else if (bid < 1664) {
        const int base = (bid - 1536) * 256 + t;
#pragma unroll
        for (int it = 0; it < 8; ++it) {
            const int g = base + it * 32768;
            float4 v = *(const float4*)(oW2 + (size_t)g * 4);
            const float* vp = (const float*)&v;
            ushort4 uh;
            uh.x = f2bf(vp[0]); uh.y = f2bf(vp[1]);
            uh.z = f2bf(vp[2]); uh.w = f2bf(vp[3]);
            *(ushort4*)(o2bf + (size_t)g * 4) = uh;
        }
    } else if (bid < 1696) {
        const int c = bid - 1664;
#pragma unroll
        for (int kk = 0; kk < 4; ++kk) {
            const int k = kk * 256 + t;
            const float v = (c < C_) ? eW2[(size_t)k * C_ + c] : 0.f;
            w2th[(size_t)c * 1024 + k] = f2bf(v);
        }
    } else if (bid < 1700) {
        const int n = (bid - 1696) * 256 + t;
        u16 buf[32];
#pragma unroll
        for (int k = 0; k < 32; ++k)
            buf[k] = (k < DIN) ? f2bf(eW1[(size_t)k * H_ + n]) : (u16)0;
#pragma unroll
        for (int q = 0; q < 4; ++q)
            *(uint4*)(e1t20 + (size_t)n * 32 + q * 8) = *(uint4*)&buf[q * 8];
    } else {
        const int r = bid - 1700, kc = r >> 2, nb = r & 3;
        const int n = nb * 256 + t;
        const int k0 = kc * 128;
        float acc = 0.f;
#pragma unroll 8
        for (int k = 0; k < 128; ++k)
            acc = fmaf(ob2[k0 + k], eW1[(size_t)(DIN + k0 + k) * H_ + n], acc);
        biasp[kc * H_ + n] = acc;
    }
}

// ---------------------------------------------------------------------------
// MFMA GEMM tile (single bf16 A): C[gm0+128, gn0+64] = A @ Bt^T (+bias).
// ---------------------------------------------------------------------------
template <int BN>
__device__ __forceinline__ void gemm_mfma_tile(
    const u16* __restrict__ A0, const u16* __restrict__ Bt,
    float* __restrict__ C, const float* __restrict__ bias,
    int ldK, int nk1, int gm0, int gn0, char* lds)
{
    constexpr int FN    = BN / 32;
    constexpr int WNw   = BN / 2;
    constexpr int BR    = BN / 64;
    constexpr int BUFSZ = 8192 + BN * 64;

    const int tid  = threadIdx.x;
    const int wave = tid >> 6, l = tid & 63, ml = l & 15, koct = l >> 4;
    const int wm = wave >> 1, wn = wave & 1;
    const int swz = koct ^ ((ml >> 1) & 3);
    const int a_ro = (wm * 64 + ml) * 64 + swz * 16;
    const int b_ro = (wn * WNw + ml) * 64 + swz * 16;

    const int sm = tid >> 2, sq = tid & 3;
    int wAo[2], wBo[BR];
    size_t gAo[2], gBo[BR];
#pragma unroll
    for (int q = 0; q < 2; ++q) {
        const int m = q * 64 + sm;
        wAo[q] = m * 64 + ((sq ^ ((m >> 1) & 3)) * 16);
        gAo[q] = (size_t)(gm0 + m) * ldK * 2 + sq * 16;
    }
#pragma unroll
    for (int q = 0; q < BR; ++q) {
        const int n = q * 64 + sm;
        wBo[q] = n * 64 + ((sq ^ ((n >> 1) & 3)) * 16);
        gBo[q] = (size_t)(gn0 + n) * ldK * 2 + sq * 16;
    }

    f32x4 acc[4][FN];
    const f32x4 zz = {0.f, 0.f, 0.f, 0.f};
#pragma unroll
    for (int i = 0; i < 4; ++i)
#pragma unroll
        for (int j = 0; j < FN; ++j) acc[i][j] = zz;

    const char* A0c = (const char*)A0;
    const char* Btc = (const char*)Bt;

    uint4 st[2 + BR];
    auto stage = [&](int kt) {
        const size_t koff = (size_t)kt * 64;
        st[0] = *(const uint4*)(A0c + gAo[0] + koff);
        st[1] = *(const uint4*)(A0c + gAo[1] + koff);
#pragma unroll
        for (int q = 0; q < BR; ++q)
            st[2 + q] = *(const uint4*)(Btc + gBo[q] + koff);
    };
    auto dswrite = [&](int buf) {
        char* d = lds + buf * BUFSZ;
        *(uint4*)(d + wAo[0]) = st[0];
        *(uint4*)(d + wAo[1]) = st[1];
#pragma unroll
        for (int q = 0; q < BR; ++q)
            *(uint4*)(d + 8192 + wBo[q]) = st[2 + q];
    };
    auto compute = [&](int buf) {
        const char* As = lds + buf * BUFSZ;
        const char* Bs = As + 8192;
        bf16x8 af[4], bfv[FN];
#pragma unroll
        for (int fm = 0; fm < 4; ++fm)
            af[fm] = *(const bf16x8*)(As + a_ro + fm * 1024);
#pragma unroll
        for (int fn = 0; fn < FN; ++fn)
            bfv[fn] = *(const bf16x8*)(Bs + b_ro + fn * 1024);
#pragma unroll
        for (int fm = 0; fm < 4; ++fm)
#pragma unroll
            for (int fn = 0; fn < FN; ++fn)
                acc[fm][fn] = __builtin_amdgcn_mfma_f32_16x16x32_bf16(
                    af[fm], bfv[fn], acc[fm][fn], 0, 0, 0);
    };

    stage(0); dswrite(0); __syncthreads();
    for (int kt = 0; kt < nk1; ++kt) {
        if (kt + 1 < nk1) stage(kt + 1);
        compute(kt & 1);
        if (kt + 1 < nk1) dswrite((kt + 1) & 1);
        __syncthreads();
    }

    float br[FN];
#pragma unroll
    for (int fn = 0; fn < FN; ++fn)
        br[fn] = bias ? bias[gn0 + wn * WNw + fn * 16 + ml] : 0.f;
#pragma unroll
    for (int fm = 0; fm < 4; ++fm) {
        const int rowb = gm0 + wm * 64 + fm * 16 + koct * 4;
#pragma unroll
        for (int fn = 0; fn < FN; ++fn) {
            const int col = gn0 + wn * WNw + fn * 16 + ml;
#pragma unroll
            for (int r = 0; r < 4; ++r)
                C[(size_t)(rowb + r) * 1024 + col] = acc[fm][fn][r] + br[fn];
        }
    }
}

// kernelA2: [0,384) GEMM1 split-K3 -> p_h1[c]; [384,512) Wc -> p_wc
__global__ __launch_bounds__(256) void kernelA2(
    const u16* __restrict__ o_bf, const u16* __restrict__ bW1t,
    const u16* __restrict__ o2bf, const u16* __restrict__ bE1t,
    float* __restrict__ p_h1, float* __restrict__ p_wc)
{
    __shared__ alignas(16) char lds[2 * 12288];
    const int bid = blockIdx.x;
    if (bid < 384) {
        const int c = bid >> 7, tl = bid & 127;
        gemm_mfma_tile<64>(o_bf + c * 1024, bW1t + c * 1024,
                           p_h1 + (size_t)c * 1048576, nullptr, 3072, 32,
                           (tl >> 4) * 128, (tl & 15) * 64, lds);
    } else {
        const int tl = bid - 384;
        gemm_mfma_tile<64>(o2bf, bE1t, p_wc, nullptr, 1024, 32,
                           (tl >> 4) * 128, (tl & 15) * 64, lds);
    }
}

// epilogue2: [0,256) h1bf; [256,512) Wct = bf16(p_wc^T); [512] biasWc sum
__global__ __launch_bounds__(256) void epilogue2(
    const float* __restrict__ p_h1, const float* __restrict__ p_wc,
    const float* __restrict__ ob1, const float* __restrict__ eb1,
    const float* __restrict__ biasp,
    u16* __restrict__ h1bf, u16* __restrict__ Wct, float* __restrict__ biasWc)
{
    __shared__ float tl[64][65];
    const int bid = blockIdx.x, t = threadIdx.x;
    if (bid < 256) {
#pragma unroll
        for (int it = 0; it < 4; ++it) {
            const int g = bid * 1024 + it * 256 + t;
            const size_t e = (size_t)g * 4;
            float4 a = *(const float4*)(p_h1 + e);
            float4 b = *(const float4*)(p_h1 + 1048576 + e);
            float4 c = *(const float4*)(p_h1 + 2097152 + e);
            float4 s = *(const float4*)(ob1 + (e & 1023));
            const float *ap = (const float*)&a, *bp = (const float*)&b,
                        *cp = (const float*)&c, *sp = (const float*)&s;
            ushort4 uh;
            u16* up = (u16*)&uh;
#pragma unroll
            for (int j = 0; j < 4; ++j)
                up[j] = f2bf(fmaxf(ap[j] + bp[j] + cp[j] + sp[j], 0.f));
            *(ushort4*)(h1bf + e) = uh;
        }
    } else if (bid < 512) {
        const int idx = bid - 256;
        const int k0 = (idx >> 4) * 64, n0 = (idx & 15) * 64;
#pragma unroll
        for (int r = 0; r < 4; ++r) {
            const int k = k0 + r * 16 + (t >> 4);
            float4 v = *(const float4*)(p_wc + (size_t)k * 1024 + n0 + (t & 15) * 4);
            const float* vp = (const float*)&v;
#pragma unroll
            for (int j = 0; j < 4; ++j)
                tl[r * 16 + (t >> 4)][(t & 15) * 4 + j] = vp[j];
        }
        __syncthreads();
#pragma unroll
        for (int r = 0; r < 4; ++r) {
            const int n = r * 16 + (t >> 4);
            ushort4 u;
            u.x = f2bf(tl[(t & 15) * 4 + 0][n]);
            u.y = f2bf(tl[(t & 15) * 4 + 1][n]);
            u.z = f2bf(tl[(t & 15) * 4 + 2][n]);
            u.w = f2bf(tl[(t & 15) * 4 + 3][n]);
            *(ushort4*)(Wct + (size_t)(n0 + n) * 1024 + k0 + (t & 15) * 4) = u;
        }
    } else {
        const int j0 = t * 4;
        float4 s = *(const float4*)(eb1 + j0);
        float* sp = (float*)&s;
#pragma unroll
        for (int kc = 0; kc < 8; ++kc) {
            float4 p = *(const float4*)(biasp + kc * H_ + j0);
            const float* pp = (const float*)&p;
#pragma unroll
            for (int i = 0; i < 4; ++i) sp[i] += pp[i];
        }
        *(float4*)(biasWc + j0) = s;
    }
}

// kernelB2 split-K2
__global__ __launch_bounds__(256) void kernelB2(
    const u16* __restrict__ h1bf, const u16* __restrict__ Wct,
    const float* __restrict__ biasWc,
    float* __restrict__ base0, float* __restrict__ base1)
{
    __shared__ alignas(16) char lds[2 * 12288];
    const int bid = blockIdx.x;
    const int p = bid >> 7, tl = bid & 127;
    gemm_mfma_tile<64>(h1bf + p * 512, Wct + p * 512,
                       p ? base1 : base0, p ? biasWc : nullptr,
                       1024, 16, (tl >> 4) * 128, (tl & 15) * 64, lds);
}

// ===========================================================================
// Phase 1 (v7): v6 structure with the VGPR cap LIFTED (launch_bounds(256,2)).
// R10's ereg preload + consumer arrays spilled to scratch at the (256,4)
// 64-VGPR cap (VGPR_Count=64, FETCH 74MB). With cap 256 everything stays in
// registers: produce = pure MFMA+VALU; consume = 2x ds_read_b128 + FMA + DPP.
// ===========================================================================
#define CPH6  16
#define CNPH6 6        // 6*16 = 96 >= 83
#define ASTR  1048     // u16 row stride (2096 B, 16B-aligned)
#define APL   528      // u16 plane stride (1056 B, 16B-aligned)

__global__ __launch_bounds__(256, 2) void chain_seq7(
    const float* __restrict__ x, const u16* __restrict__ e1t20,
    const float* __restrict__ eW1, const float* __restrict__ eW2,
    const float* __restrict__ eb2,
    const float* __restrict__ base0, const float* __restrict__ base1,
    float* __restrict__ cur0_buf)
{
    __shared__ alignas(16) u16 A_bf[CPH6 * ASTR];   // 33,536 B
    __shared__ float xl[T_ * DIN];                  // 6,800 B

    const int b = blockIdx.x, tid = threadIdx.x;
    const int w = tid >> 6, l = tid & 63;
    const int ml = l & 15, koct = l >> 4;

    for (int i = tid; i < T_ * DIN; i += 256)
        xl[i] = x[(size_t)b * (T_ * DIN) + i];

    const f32x4 zz = {0.f, 0.f, 0.f, 0.f};

    // ---- producer registers: e1t20 slice (static-indexed, fully unrolled) --
    bf16x8 ereg[22];
    if (w) {
#pragma unroll
        for (int q = 0; q < 22; ++q) {
            const int jt = (w - 1) + 3 * q;
            if (jt < 64)
                ereg[q] = *(const bf16x8*)
                    &e1t20[(size_t)(jt * 16 + ml) * 32 + koct * 8];
        }
    }

    // ---- consumer registers ----
    float u[16], v[16], baseR[16];
    float prev = 0.f, cur0_init = 0.f;
    if (w == 0) {
        const int j0 = l * 16;
#pragma unroll
        for (int i = 0; i < 16; i += 4)
            *(float4*)&u[i] = *(const float4*)&eW1[j0 + i];
#pragma unroll
        for (int i = 0; i < 16; ++i)
            v[i] = eW2[(size_t)(j0 + i) * C_];
#pragma unroll
        for (int i = 0; i < 16; i += 4) {
            float4 b0v = *(const float4*)&base0[(size_t)b * H_ + j0 + i];
            float4 b1v = *(const float4*)&base1[(size_t)b * H_ + j0 + i];
            baseR[i + 0] = b0v.x + b1v.x;
            baseR[i + 1] = b0v.y + b1v.y;
            baseR[i + 2] = b0v.z + b1v.z;
            baseR[i + 3] = b0v.w + b1v.w;
        }
        cur0_init = x[(size_t)b * (T_ * DIN)];
    }
    __syncthreads();   // xl ready

    const float eb20 = eb2[0];
    float* cb = cur0_buf + (size_t)b * TOUT;
    int t = 0;

#pragma unroll 1
    for (int ph = 0; ph < CNPH6; ++ph) {
        const int t0 = ph * CPH6;

        // ---- produce phase ph (waves 1-3; pure MFMA+VALU, no memory) ----
        if (w) {
            u16 hw[8];
            const int tg = t0 + ml;
#pragma unroll
            for (int e = 0; e < 8; ++e) {
                const int k = koct * 8 + e;
                float vx = 0.f;
                if (k >= 1 && k < DIN && tg < T_) vx = xl[tg * DIN + k];
                hw[e] = f2bf(vx);
            }
            bf16x8 af;
            {
                uint4 pk;
                pk.x = hw[0] | ((unsigned)hw[1] << 16);
                pk.y = hw[2] | ((unsigned)hw[3] << 16);
                pk.z = hw[4] | ((unsigned)hw[5] << 16);
                pk.w = hw[6] | ((unsigned)hw[7] << 16);
                af = *(bf16x8*)&pk;
            }
            const int wbase = (ml >> 3) * APL + (ml & 7);
#pragma unroll
            for (int q = 0; q < 22; ++q) {
                const int jt = (w - 1) + 3 * q;
                if (jt < 64) {
                    f32x4 c = __builtin_amdgcn_mfma_f32_16x16x32_bf16(
                        af, ereg[q], zz, 0, 0, 0);
#pragma unroll
                    for (int r = 0; r < 4; ++r) {
                        const int row = koct * 4 + r;
                        A_bf[row * ASTR + wbase + jt * 8] = f2bf(c[r]);
                    }
                }
            }
        }
        __syncthreads();   // A ready

        // ---- consume (wave 0): serial steps ----
        if (w == 0) {
            const int rem = 83 - t0;
            const int nst = (rem < CPH6) ? rem : CPH6;

            uint4 ra = *(const uint4*)&A_bf[l * 8];
            uint4 rb = *(const uint4*)&A_bf[APL + l * 8];
            float ab[16];
            {
                const u16* pa = (const u16*)&ra;
                const u16* pb = (const u16*)&rb;
#pragma unroll
                for (int i = 0; i < 8; ++i) {
                    ab[i]     = bf2f(pa[i]) + baseR[i];
                    ab[8 + i] = bf2f(pb[i]) + baseR[8 + i];
                }
            }

            for (int sl = 0; sl < nst; ++sl, ++t) {
                const int sln = (sl + 1 < nst) ? sl + 1 : sl;
                uint4 rna = *(const uint4*)&A_bf[sln * ASTR + l * 8];
                uint4 rnb = *(const uint4*)&A_bf[sln * ASTR + APL + l * 8];

                const float cur0 = (t == 0) ? cur0_init : prev;
                if (l == 0) cb[t] = cur0;

                float p0 = 0.f, p1 = 0.f, p2 = 0.f, p3 = 0.f;
#pragma unroll
                for (int i = 0; i < 16; i += 4) {
                    p0 = fmaf(fmaxf(fmaf(cur0, u[i + 0], ab[i + 0]), 0.f), v[i + 0], p0);
                    p1 = fmaf(fmaxf(fmaf(cur0, u[i + 1], ab[i + 1]), 0.f), v[i + 1], p1);
                    p2 = fmaf(fmaxf(fmaf(cur0, u[i + 2], ab[i + 2]), 0.f), v[i + 2], p2);
                    p3 = fmaf(fmaxf(fmaf(cur0, u[i + 3], ab[i + 3]), 0.f), v[i + 3], p3);
                }
                prev = eb20 + wave64_sum_bcast((p0 + p1) + (p2 + p3));

                {   // convert prefetched next row (off the dependent chain)
                    const u16* pa = (const u16*)&rna;
                    const u16* pb = (const u16*)&rnb;
#pragma unroll
                    for (int i = 0; i < 8; ++i) {
                        ab[i]     = bf2f(pa[i]) + baseR[i];
                        ab[8 + i] = bf2f(pb[i]) + baseR[8 + i];
                    }
                }
            }
        }
        __syncthreads();   // consumer done with A before next produce
    }
    if (w == 0 && l == 0) cb[TOUT - 1] = prev;
}

// ===========================================================================
// Phase 2: parallel expansion (unchanged).
// ===========================================================================
__global__ __launch_bounds__(256, 4) void expand(
    const float* __restrict__ x, const float* __restrict__ base0,
    const float* __restrict__ base1, const float* __restrict__ cur0_buf,
    const u16* __restrict__ e1t20, const u16* __restrict__ w2th,
    const float* __restrict__ eb2, float* __restrict__ out)
{
    __shared__ u16 A_lds[64 * 32];
    __shared__ u16 e_lds[128 * 32];
    __shared__ u16 h_lds[64 * 128];
    __shared__ u16 w2_s[32 * 128];
    __shared__ float base_s[2 * 128];

    const int tid = threadIdx.x;
    const int g0 = blockIdx.x * 64;
    const int w = tid >> 6, l = tid & 63, ml = l & 15, koct = l >> 4;
    const int b0 = g0 / 84;
    const int b1 = (b0 + 1 < B_) ? b0 + 1 : b0;

    {
        const int row = tid >> 2, q = tid & 3;
        const int g = g0 + row, bb = g / 84, tt = g - bb * 84;
        u16 hw[8];
#pragma unroll
        for (int c = 0; c < 8; ++c) {
            const int k = q * 8 + c;
            float v = 0.f;
            if (k == 0) v = cur0_buf[g];
            else if (k < DIN) v = x[(size_t)bb * (T_ * DIN) + tt * DIN + k];
            hw[c] = f2bf(v);
        }
        uint4 pk;
        pk.x = hw[0] | ((unsigned)hw[1] << 16);
        pk.y = hw[2] | ((unsigned)hw[3] << 16);
        pk.z = hw[4] | ((unsigned)hw[5] << 16);
        pk.w = hw[6] | ((unsigned)hw[7] << 16);
        *(uint4*)&A_lds[row * 32 + q * 8] = pk;
    }

    const int grow = w * 16 + ml;
    const int g = g0 + grow;
    const int sel = g / 84 - b0;
    __syncthreads();
    const bf16x8 xfrag = *(const bf16x8*)&A_lds[grow * 32 + koct * 8];

    f32x4 acc[2];
    const f32x4 zz = {0.f, 0.f, 0.f, 0.f};
    acc[0] = zz; acc[1] = zz;

#pragma unroll 1
    for (int kc = 0; kc < 8; ++kc) {
        const int n0 = kc * 128;
        if (kc) __syncthreads();
        {
            const u16* src = e1t20 + n0 * 32 + tid * 16;
            *(uint4*)&e_lds[tid * 16]     = *(const uint4*)src;
            *(uint4*)&e_lds[tid * 16 + 8] = *(const uint4*)(src + 8);
        }
        {
            const int wr = tid >> 3, sg = tid & 7;
            const u16* srcw = w2th + (size_t)wr * 1024 + n0 + sg * 16;
            const int s0 = (sg * 2) ^ (wr & 15), s1 = (sg * 2 + 1) ^ (wr & 15);
            *(uint4*)&w2_s[wr * 128 + s0 * 8] = *(const uint4*)srcw;
            *(uint4*)&w2_s[wr * 128 + s1 * 8] = *(const uint4*)(srcw + 8);
        }
        {
            const int bs = tid >> 7, c = tid & 127;
            const size_t rb = (size_t)(bs ? b1 : b0) * H_ + n0 + c;
            base_s[bs * 128 + c] = base0[rb] + base1[rb];
        }
        __syncthreads();

#pragma unroll
        for (int p = 0; p < 8; ++p) {
            const bf16x8 ef = *(const bf16x8*)&e_lds[(p * 16 + ml) * 32 + koct * 8];
            f32x4 c1 = zz;
            c1 = __builtin_amdgcn_mfma_f32_16x16x32_bf16(ef, xfrag, c1, 0, 0, 0);
            u16 hq[4];
#pragma unroll
            for (int q = 0; q < 4; ++q) {
                const int j = p * 16 + koct * 4 + q;
                const float v = c1[q] + base_s[sel * 128 + j];
                hq[q] = f2bf(fmaxf(v, 0.f));
            }
            uint2 pk;
            pk.x = hq[0] | ((unsigned)hq[1] << 16);
            pk.y = hq[2] | ((unsigned)hq[3] << 16);
            const int s16 = (p * 2 + (koct >> 1)) ^ ml;
            *(uint2*)&h_lds[grow * 128 + s16 * 8 + (koct & 1) * 4] = pk;
        }

#pragma unroll
        for (int ks = 0; ks < 4; ++ks) {
            const int sl = (((ks * 4 + koct) ^ ml)) * 8;
            const bf16x8 hf = *(const bf16x8*)&h_lds[grow * 128 + sl];
#pragma unroll
            for (int ct = 0; ct < 2; ++ct) {
                const bf16x8 wf = *(const bf16x8*)&w2_s[(ct * 16 + ml) * 128 + sl];
                acc[ct] = __builtin_amdgcn_mfma_f32_16x16x32_bf16(
                    wf, hf, acc[ct], 0, 0, 0);
            }
        }
    }

#pragma unroll
    for (int ct = 0; ct < 2; ++ct) {
#pragma unroll
        for (int q = 0; q < 4; ++q) {
            const int c = ct * 16 + koct * 4 + q;
            if (c < C_)
                out[(size_t)g * C_ + c] = acc[ct][q] + eb2[c];
        }
    }
}

// ===========================================================================
// FALLBACK fp32 path — used only if ws is too small.
// ===========================================================================
struct GemmSmem {
    float As[2][16][68];
    float Bs[2][16][64];
};

template <int RELU>
__device__ __forceinline__ void gemm_core(
    const float* __restrict__ A, int lda,
    const float* __restrict__ Bm, int ldb,
    const float* __restrict__ bias, const float* __restrict__ bias_parts,
    float* __restrict__ Cc, int ldc, int K, int tile, GemmSmem& sm)
{
    const int tid = threadIdx.x;
    const int bm = (tile >> 4) * 64, bn = (tile & 15) * 64;
    const int wave = tid >> 6, l = tid & 63;
    const int n0 = (wave & 1) * 32 + (l & 7) * 4;
    const int m0 = (wave >> 1) * 32 + (l >> 3) * 4;
    const int am = tid >> 2, akq = tid & 3;
    const int bk = tid >> 4, bnq = tid & 15;
    const float* Arow = A + (size_t)(bm + am) * lda + akq * 4;
    const float* Brow = Bm + (size_t)bk * ldb + bn + bnq * 4;
    float acc[4][4] = {};
    const int nIter = (K + 15) >> 4;
    {
        const int ak = akq * 4;
        float4 av = (ak + 4 <= K) ? *(const float4*)(Arow)
                                  : make_float4(0.f, 0.f, 0.f, 0.f);
        float4 bv = (bk < K) ? *(const float4*)(Brow)
                             : make_float4(0.f, 0.f, 0.f, 0.f);
        sm.As[0][akq * 4 + 0][am] = av.x; sm.As[0][akq * 4 + 1][am] = av.y;
        sm.As[0][akq * 4 + 2][am] = av.z; sm.As[0][akq * 4 + 3][am] = av.w;
        *(float4*)&sm.Bs[0][bk][bnq * 4] = bv;
    }
    __syncthreads();
    for (int it = 0; it < nIter; ++it) {
        const int cur = it & 1;
        const bool pf = (it + 1 < nIter);
        float4 pav, pbv;
        if (pf) {
            const int k0 = (it + 1) << 4, ak = k0 + akq * 4;
            pav = (ak + 4 <= K) ? *(const float4*)(Arow + k0)
                                : make_float4(0.f, 0.f, 0.f, 0.f);
            pbv = (k0 + bk < K) ? *(const float4*)(Brow + (size_t)k0 * ldb)
                                : make_float4(0.f, 0.f, 0.f, 0.f);
        }
#pragma unroll
        for (int kk = 0; kk < 16; ++kk) {
            float ar[4], br[4];
            *(float4*)ar = *(const float4*)&sm.As[cur][kk][m0];
            *(float4*)br = *(const float4*)&sm.Bs[cur][kk][n0];
#pragma unroll
            for (int r = 0; r < 4; ++r)
#pragma unroll
                for (int c = 0; c < 4; ++c)
                    acc[r][c] = fmaf(ar[r], br[c], acc[r][c]);
        }
        if (pf) {
            const int nb = cur ^ 1;
            sm.As[nb][akq * 4 + 0][am] = pav.x; sm.As[nb][akq * 4 + 1][am] = pav.y;
            sm.As[nb][akq * 4 + 2][am] = pav.z; sm.As[nb][akq * 4 + 3][am] = pav.w;
            *(float4*)&sm.Bs[nb][bk][bnq * 4] = pbv;
        }
        __syncthreads();
    }
    float bias4[4];
#pragma unroll
    for (int c = 0; c < 4; ++c) {
        const int col = bn + n0 + c;
        float b = bias ? bias[col] : 0.f;
        if (bias_parts)
#pragma unroll
            for (int p = 0; p < 8; ++p) b += bias_parts[p * H_ + col];
        bias4[c] = b;
    }
#pragma unroll
    for (int r = 0; r < 4; ++r) {
        float4 v; float* vp = (float*)&v;
#pragma unroll
        for (int c = 0; c < 4; ++c) {
            float t2 = acc[r][c] + bias4[c];
            if (RELU) t2 = fmaxf(t2, 0.f);
            vp[c] = t2;
        }
        *(float4*)&Cc[(size_t)(bm + m0 + r) * ldc + bn + n0] = v;
    }
}

__global__ __launch_bounds__(256) void kernelA_fb(
    const float* __restrict__ o, const float* __restrict__ oW1,
    const float* __restrict__ ob1, const float* __restrict__ oW2,
    const float* __restrict__ eW1, const float* __restrict__ ob2,
    float* __restrict__ h1, float* __restrict__ Wc, float* __restrict__ biasc)
{
    __shared__ GemmSmem sm;
    const int bid = blockIdx.x;
    if (bid < 256) {
        gemm_core<1>(o, OBJ_, oW1, H_, ob1, nullptr, h1, H_, OBJ_, bid, sm);
    } else if (bid < 512) {
        gemm_core<0>(oW2, H_, eW1 + (size_t)DIN * H_, H_, nullptr, nullptr,
                     Wc, H_, H_, bid - 256, sm);
    } else {
        const int r = bid - 512, kc = r >> 2, nb = r & 3;
        const int n = nb * 256 + (int)threadIdx.x;
        const int k0 = kc * 128;
        float acc = 0.f;
#pragma unroll 8
        for (int k = 0; k < 128; ++k)
            acc = fmaf(ob2[k0 + k], eW1[(size_t)(DIN + k0 + k) * H_ + n], acc);
        biasc[kc * H_ + n] = acc;
    }
}

__global__ __launch_bounds__(256) void kernelB_fb(
    const float* __restrict__ h1, const float* __restrict__ Wc,
    const float* __restrict__ eb1, const float* __restrict__ biasc,
    float* __restrict__ base0)
{
    __shared__ GemmSmem sm;
    gemm_core<0>(h1, H_, Wc, H_, eb1, biasc, base0, H_, H_, blockIdx.x, sm);
}

__global__ __launch_bounds__(256, 2) void expert_seq_fb(
    const float* __restrict__ x, const float* __restrict__ eW1,
    const float* __restrict__ eW2, const float* __restrict__ eb2,
    const float* __restrict__ base0, float* __restrict__ out)
{
    const int b   = blockIdx.x;
    const int tid = threadIdx.x;
    const int j0  = tid * 4;

    __shared__ float xl[T_ * DIN];
    __shared__ float pl[256 * 29];
    __shared__ float pl2[256];
    __shared__ float prevs;

    for (int idx = tid; idx < T_ * DIN; idx += 256)
        xl[idx] = x[(size_t)b * (T_ * DIN) + idx];

    float w1r[DIN][4];
#pragma unroll
    for (int d = 0; d < DIN; ++d)
        *(float4*)w1r[d] = *(const float4*)&eW1[(size_t)d * H_ + j0];

    float base_r[4];
    *(float4*)base_r = *(const float4*)&base0[(size_t)b * H_ + j0];

    float w2r[4][C_];
#pragma unroll
    for (int i = 0; i < 4; ++i)
#pragma unroll
        for (int c = 0; c < C_; ++c)
            w2r[i][c] = eW2[(size_t)(j0 + i) * C_ + c];

    const float myb = (tid < C_) ? eb2[tid] : 0.f;
    __syncthreads();

    float prev = 0.f;
#pragma unroll 1
    for (int t = 0; t < TOUT; ++t) {
        const float cur0 = (t == 0) ? xl[0] : prev;
        float h[4];
#pragma unroll
        for (int i = 0; i < 4; ++i)
            h[i] = fmaf(cur0, w1r[0][i], base_r[i]);
#pragma unroll
        for (int d = 1; d < DIN; ++d) {
            const float xv = xl[t * DIN + d];
#pragma unroll
            for (int i = 0; i < 4; ++i)
                h[i] = fmaf(xv, w1r[d][i], h[i]);
        }
#pragma unroll
        for (int i = 0; i < 4; ++i)
            h[i] = fmaxf(h[i], 0.f);
        float p[C_];
#pragma unroll
        for (int c = 0; c < C_; ++c)
            p[c] = h[0] * w2r[0][c];
#pragma unroll
        for (int i = 1; i < 4; ++i)
#pragma unroll
            for (int c = 0; c < C_; ++c)
                p[c] = fmaf(h[i], w2r[i][c], p[c]);
#pragma unroll
        for (int c = 0; c < C_; ++c)
            pl[tid * 29 + c] = p[c];
        __syncthreads();
        {
            const int c2 = tid & 31, grp = tid >> 5;
            float s = 0.f;
            if (c2 < C_) {
                const int basei = grp * 32 * 29 + c2;
#pragma unroll
                for (int s2 = 0; s2 < 32; ++s2)
                    s += pl[basei + s2 * 29];
            }
            pl2[tid] = s;
        }
        __syncthreads();
        if (tid < C_) {
            float o = myb;
#pragma unroll
            for (int g = 0; g < 8; ++g)
                o += pl2[g * 32 + tid];
            out[((size_t)b * TOUT + t) * C_ + tid] = o;
            if (tid == 0) prevs = o;
        }
        __syncthreads();
        prev = prevs;
    }
}

// ===========================================================================
extern "C" void kernel_launch(void* const* d_in, const int* in_sizes, int n_in,
                              void* d_out, int out_size, void* d_ws, size_t ws_size,
                              hipStream_t stream)
{
    const float* o   = (const float*)d_in[0];
    const float* x   = (const float*)d_in[1];
    const float* oW1 = (const float*)d_in[2];
    const float* ob1 = (const float*)d_in[3];
    const float* oW2 = (const float*)d_in[4];
    const float* ob2 = (const float*)d_in[5];
    const float* eW1 = (const float*)d_in[6];
    const float* eb1 = (const float*)d_in[7];
    const float* eW2 = (const float*)d_in[8];
    const float* eb2 = (const float*)d_in[9];

    float* outp = (float*)d_out;
    float* ws   = (float*)d_ws;
    dim3 blk(256);

    const size_t NEED2 = 38326272;
    if (ws_size >= NEED2) {
        float* p_h1   = ws;                       // 3*1048576 f
        float* p_wc   = ws + 3145728;             // 1048576 f
        float* biasWc = ws + 4194304;             // 1024 f
        float* cur0b  = ws + 4195328;             // 86016 f
        float* biasp  = ws + 4281344;             // 8192 f
        u16*   ub     = (u16*)(ws + 4289536);
        u16 *o_bf  = ub,             *bW1t = ub + 3145728;
        u16 *bE1t  = ub + 6291456,   *o2bf = ub + 7340032;
        u16 *h1bf  = ub + 8388608,   *Wct  = ub + 9437184;
        u16 *w2th  = ub + 10485760;
        u16 *e1t20 = ub + 10551296;
        float* base0 = p_h1;          // reuse p_h1 after epilogue2 consumed it
        float* base1 = p_h1 + 1048576;

        convertK2<<<dim3(1732), blk, 0, stream>>>(o, oW1, eW1, oW2, eW2, ob2,
                                                  o_bf, bW1t, bE1t, o2bf,
                                                  w2th, e1t20, biasp);
        kernelA2<<<dim3(512), blk, 0, stream>>>(o_bf, bW1t, o2bf, bE1t,
                                                p_h1, p_wc);
        epilogue2<<<dim3(513), blk, 0, stream>>>(p_h1, p_wc, ob1, eb1, biasp,
                                                 h1bf, Wct, biasWc);
        kernelB2<<<dim3(256), blk, 0, stream>>>(h1bf, Wct, biasWc,
                                                base0, base1);
        chain_seq7<<<dim3(B_), blk, 0, stream>>>(x, e1t20, eW1, eW2, eb2,
                                                 base0, base1, cur0b);
        expand<<<dim3(1344), blk, 0, stream>>>(x, base0, base1, cur0b, e1t20,
                                               w2th, eb2, outp);
    } else {
        const size_t MF = (size_t)H_ * H_;
        float* h1    = ws;
        float* Wc    = ws + MF;
        float* base0 = ws + 2 * MF;
        float* biasc = outp;
        kernelA_fb<<<dim3(544), blk, 0, stream>>>(o, oW1, ob1, oW2, eW1, ob2,
                                                  h1, Wc, biasc);
        kernelB_fb<<<dim3(256), blk, 0, stream>>>(h1, Wc, eb1, biasc, base0);
        expert_seq_fb<<<dim3(B_), blk, 0, stream>>>(x, eW1, eW2, eb2,
                                                    base0, outp);
    }
}